// Round 1
// baseline (4076.481 us; speedup 1.0000x reference)
//
#include <hip/hip_runtime.h>
#include <stdint.h>

typedef unsigned short u16;
typedef __attribute__((ext_vector_type(8))) __bf16 bf16x8;
typedef __attribute__((ext_vector_type(4))) float floatx4;

#define KLAYERS 8
#define KHEADS  16
#define KDM     1024
#define KDFF    4096
#define KDH     64
#define KBATCH  2
#define KNV     256
#define KTTEXT  1792
#define KT      2048
#define KBT     (KBATCH * KT)       /* 4096 */
#define KMTXT   (KBATCH * KTTEXT)   /* 3584 */
#define KVOCAB  32000

static __device__ __forceinline__ u16 f2bf(float f) {
  union { float f; uint32_t u; } v; v.f = f;
  return (u16)((v.u + 0x7fffu + ((v.u >> 16) & 1u)) >> 16);
}

// async global->LDS, 16B per lane; LDS dest = wave-uniform base + lane*16
static __device__ __forceinline__ void async_ld16(const void* g, void* l) {
  __builtin_amdgcn_global_load_lds((__attribute__((address_space(1))) void*)g,
                                   (__attribute__((address_space(3))) void*)l,
                                   16, 0, 0);
}

// ---------------------------------------------------------------- convert
__global__ __launch_bounds__(256) void f32_to_bf16_k(const float* __restrict__ in,
                                                     u16* __restrict__ out, int n4) {
  int i = blockIdx.x * 256 + threadIdx.x;
  if (i < n4) {
    float4 v = ((const float4*)in)[i];
    ushort4 o;
    o.x = f2bf(v.x); o.y = f2bf(v.y); o.z = f2bf(v.z); o.w = f2bf(v.w);
    ((ushort4*)out)[i] = o;
  }
}

// ---------------------------------------------------------------- embed
__global__ __launch_bounds__(256) void embed_k(const int* __restrict__ idx,
                                               const float* __restrict__ img,
                                               const float* __restrict__ tok,
                                               const float* __restrict__ pos,
                                               float* __restrict__ x) {
  int i = blockIdx.x * 256 + threadIdx.x;        // float4 index, total KBT*KDM/4
  int d4 = KDM / 4;
  int row = i / d4, c4 = i - row * d4;
  int b = row >> 11, t = row & (KT - 1);
  float4 v;
  if (t < KNV) {
    v = ((const float4*)(img + ((size_t)(b * KNV + t)) * KDM))[c4];
  } else {
    int tk = idx[b * KTTEXT + (t - KNV)];
    v = ((const float4*)(tok + (size_t)tk * KDM))[c4];
  }
  float4 p = ((const float4*)(pos + (size_t)t * KDM))[c4];
  v.x += p.x; v.y += p.y; v.z += p.z; v.w += p.w;
  ((float4*)x)[i] = v;
}

// ---------------------------------------------------------------- layernorm -> bf16
__global__ __launch_bounds__(256) void layernorm_k(const float* __restrict__ x,
                                                   const float* __restrict__ w,
                                                   const float* __restrict__ bias,
                                                   u16* __restrict__ out, int textOnly) {
  int row = blockIdx.x;
  int xrow = row;
  if (textOnly) { int b = row / KTTEXT; int tt = row - b * KTTEXT; xrow = b * KT + KNV + tt; }
  const float* xp = x + (size_t)xrow * KDM;
  int tid = threadIdx.x;
  float4 v = ((const float4*)xp)[tid];
  float s  = v.x + v.y + v.z + v.w;
  float sq = v.x * v.x + v.y * v.y + v.z * v.z + v.w * v.w;
  for (int off = 1; off < 64; off <<= 1) { s += __shfl_xor(s, off); sq += __shfl_xor(sq, off); }
  __shared__ float ls[8];
  int wave = tid >> 6, lane = tid & 63;
  if (lane == 0) { ls[wave] = s; ls[4 + wave] = sq; }
  __syncthreads();
  s  = ls[0] + ls[1] + ls[2] + ls[3];
  sq = ls[4] + ls[5] + ls[6] + ls[7];
  float mu  = s * (1.0f / KDM);
  float var = sq * (1.0f / KDM) - mu * mu;
  float inv = rsqrtf(var + 1e-5f);
  float4 wv = ((const float4*)w)[tid];
  float4 bv = ((const float4*)bias)[tid];
  ushort4 o;
  o.x = f2bf((v.x - mu) * inv * wv.x + bv.x);
  o.y = f2bf((v.y - mu) * inv * wv.y + bv.y);
  o.z = f2bf((v.z - mu) * inv * wv.z + bv.z);
  o.w = f2bf((v.w - mu) * inv * wv.w + bv.w);
  ((ushort4*)(out + (size_t)row * KDM))[tid] = o;
}

// ---------------------------------------------------------------- GEMM (NT): C[M,N] = A[M,K] * B[N,K]^T
// 128x128 tile, BK=32, 4 waves (2x2 of 64x64), mfma 16x16x32 bf16. M,N %128==0, K%32==0.
// Fused epilogues:
//   MODE 0: Cf[gm*N+gn] = acc                      (fp32 out)
//   MODE 1: O16 = relu(acc + bias[gn]) bf16        (FC1)
//   MODE 2: Cf[gm*N+gn] += acc (+bias[gn])         (residual into x)
//   MODE 3: QKV repack -> Qo (x0.125), Ko, Vto     (N==3072)
template<int MODE>
__global__ __launch_bounds__(256) void gemm_nt(const u16* __restrict__ A,
                                               const u16* __restrict__ B,
                                               int N, int K,
                                               float* __restrict__ Cf,
                                               const float* __restrict__ bias,
                                               u16* __restrict__ O16,
                                               u16* __restrict__ Qo,
                                               u16* __restrict__ Ko,
                                               u16* __restrict__ Vto) {
  __shared__ alignas(16) u16 At[128 * 32];
  __shared__ alignas(16) u16 Bt[128 * 32];
  const int tid  = threadIdx.x;
  const int wave = tid >> 6, lane = tid & 63;
  const int quad = lane >> 4, l16 = lane & 15;
  const int m0 = blockIdx.y << 7, n0 = blockIdx.x << 7;
  const int wm = (wave >> 1) << 6, wn = (wave & 1) << 6;
  const u16* Ap = A + (size_t)m0 * K;
  const u16* Bp = B + (size_t)n0 * K;
  const int r0 = tid >> 2, c0 = (tid & 3) << 3;   // 16B chunk: row r, k-offset c
  const int r1 = r0 + 64;
  floatx4 acc[4][4];
  const floatx4 fz = {0.f, 0.f, 0.f, 0.f};
#pragma unroll
  for (int i = 0; i < 4; ++i)
#pragma unroll
    for (int j = 0; j < 4; ++j) acc[i][j] = fz;

  for (int kb = 0; kb < K; kb += 32) {
    __syncthreads();
    async_ld16(Ap + (size_t)r0 * K + kb + c0, At + wave * 512);
    async_ld16(Ap + (size_t)r1 * K + kb + c0, At + 2048 + wave * 512);
    async_ld16(Bp + (size_t)r0 * K + kb + c0, Bt + wave * 512);
    async_ld16(Bp + (size_t)r1 * K + kb + c0, Bt + 2048 + wave * 512);
    __syncthreads();
    bf16x8 af[4], bfv[4];
#pragma unroll
    for (int mi = 0; mi < 4; ++mi)
      af[mi] = *(const bf16x8*)(At + (wm + mi * 16 + l16) * 32 + quad * 8);
#pragma unroll
    for (int ni = 0; ni < 4; ++ni)
      bfv[ni] = *(const bf16x8*)(Bt + (wn + ni * 16 + l16) * 32 + quad * 8);
#pragma unroll
    for (int mi = 0; mi < 4; ++mi)
#pragma unroll
      for (int ni = 0; ni < 4; ++ni)
        acc[mi][ni] = __builtin_amdgcn_mfma_f32_16x16x32_bf16(af[mi], bfv[ni], acc[mi][ni], 0, 0, 0);
  }
  // C/D layout: col = lane&15, row = quad*4 + reg  [verified m89/m91]
#pragma unroll
  for (int mi = 0; mi < 4; ++mi) {
    const int gm = m0 + wm + mi * 16 + quad * 4;
#pragma unroll
    for (int ni = 0; ni < 4; ++ni) {
      const int gn = n0 + wn + ni * 16 + l16;
      if (MODE == 0) {
        float* cp = Cf + (size_t)gm * N + gn;
#pragma unroll
        for (int r = 0; r < 4; ++r) cp[(size_t)r * N] = acc[mi][ni][r];
      } else if (MODE == 1) {
        const float bv = bias[gn];
        u16* op = O16 + (size_t)gm * N + gn;
#pragma unroll
        for (int r = 0; r < 4; ++r) {
          float a = acc[mi][ni][r] + bv;
          op[(size_t)r * N] = f2bf(a > 0.f ? a : 0.f);
        }
      } else if (MODE == 2) {
        const float bv = bias ? bias[gn] : 0.f;
        float* cp = Cf + (size_t)gm * N + gn;
#pragma unroll
        for (int r = 0; r < 4; ++r) cp[(size_t)r * N] += acc[mi][ni][r] + bv;
      } else {
        // qkv repack: gn -> (which, h, dh); row -> (b, t)
        const int which = gn >> 10, h = (gn >> 6) & (KHEADS - 1), dh = gn & (KDH - 1);
#pragma unroll
        for (int r = 0; r < 4; ++r) {
          const int row = gm + r;
          const int b = row >> 11, t = row & (KT - 1);
          const size_t bh = (size_t)(b * KHEADS + h);
          const float v = acc[mi][ni][r];
          if (which == 0)      Qo[(bh * KT + t) * KDH + dh] = f2bf(v * 0.125f);
          else if (which == 1) Ko[(bh * KT + t) * KDH + dh] = f2bf(v);
          else                 Vto[(bh * KDH + dh) * KT + t] = f2bf(v);
        }
      }
    }
  }
}

// ---------------------------------------------------------------- flash attention
// grid (T/64, B*H), block 256. Q pre-scaled. Writes O as [B,T,D] bf16.
__global__ __launch_bounds__(256) void attn_k(const u16* __restrict__ Q,
                                              const u16* __restrict__ K,
                                              const u16* __restrict__ Vt,
                                              u16* __restrict__ O) {
  __shared__ alignas(16) u16 Kt[64 * 64];      // [key][dh], chunk-swizzled
  __shared__ alignas(16) u16 Vts[64 * 64];     // [dh][key], chunk-swizzled
  __shared__ alignas(16) u16 Pt[4][16 * 64];   // per-wave P [q][key], chunk-swizzled
  const int bh = blockIdx.y;
  const int b = bh >> 4, h = bh & (KHEADS - 1);
  const int q0 = blockIdx.x << 6;
  const int tid = threadIdx.x;
  const int wave = tid >> 6, lane = tid & 63;
  const int quad = lane >> 4, l16 = lane & 15;
  const u16* Qp = Q + (size_t)bh * KT * KDH;
  const u16* Kp = K + (size_t)bh * KT * KDH;
  const u16* Vp = Vt + (size_t)bh * KDH * KT;
  u16* Op = O + (size_t)b * KT * KDM + h * KDH;

  const int qrow = q0 + wave * 16 + l16;
  bf16x8 qf0 = *(const bf16x8*)(Qp + (size_t)qrow * KDH + quad * 8);
  bf16x8 qf1 = *(const bf16x8*)(Qp + (size_t)qrow * KDH + 32 + quad * 8);

  float m_i[4], l_i[4];
  floatx4 oacc[4];
  const floatx4 fz = {0.f, 0.f, 0.f, 0.f};
#pragma unroll
  for (int r = 0; r < 4; ++r) { m_i[r] = -1e30f; l_i[r] = 0.f; }
#pragma unroll
  for (int dg = 0; dg < 4; ++dg) oacc[dg] = fz;

  const bool causal = (q0 >= KNV);
  const int ntiles = causal ? (q0 >> 6) + 1 : (KT / 64);
  u16* Pw = &Pt[wave][0];

  // staging indices (XOR chunk swizzle keyed on row&7)
  const int i0 = tid, i1 = tid + 256;
  const int sr0 = i0 >> 3, sc0 = ((i0 & 7) ^ (sr0 & 7)) << 3;
  const int sr1 = i1 >> 3, sc1 = ((i1 & 7) ^ (sr1 & 7)) << 3;

  for (int kt = 0; kt < ntiles; ++kt) {
    const int k0 = kt << 6;
    __syncthreads();
    async_ld16(Kp + (size_t)(k0 + sr0) * KDH + sc0, Kt + wave * 512);
    async_ld16(Kp + (size_t)(k0 + sr1) * KDH + sc1, Kt + 2048 + wave * 512);
    async_ld16(Vp + (size_t)sr0 * KT + k0 + sc0, Vts + wave * 512);
    async_ld16(Vp + (size_t)sr1 * KT + k0 + sc1, Vts + 2048 + wave * 512);
    __syncthreads();

    // S = Q K^T  (S[row=q(quad*4+r)][col=key(l16)] per key-group kg)
    floatx4 sk[4];
#pragma unroll
    for (int kg = 0; kg < 4; ++kg) {
      const int krow = kg * 16 + l16;
      const int sw = krow & 7;
      bf16x8 b0 = *(const bf16x8*)(Kt + krow * 64 + ((quad ^ sw) << 3));
      bf16x8 b1 = *(const bf16x8*)(Kt + krow * 64 + (((4 + quad) ^ sw) << 3));
      floatx4 z = __builtin_amdgcn_mfma_f32_16x16x32_bf16(qf0, b0, fz, 0, 0, 0);
      sk[kg] = __builtin_amdgcn_mfma_f32_16x16x32_bf16(qf1, b1, z, 0, 0, 0);
    }
    if (causal && kt == ntiles - 1) {
#pragma unroll
      for (int kg = 0; kg < 4; ++kg) {
        const int kk = k0 + kg * 16 + l16;
#pragma unroll
        for (int r = 0; r < 4; ++r) {
          const int qq = q0 + wave * 16 + quad * 4 + r;
          if (kk > qq) sk[kg][r] = -1e30f;
        }
      }
    }
    // online softmax over rows (row stats live replicated across the 16 l16 lanes)
    float mnew[4], alpha[4];
#pragma unroll
    for (int r = 0; r < 4; ++r) {
      float mx = fmaxf(fmaxf(sk[0][r], sk[1][r]), fmaxf(sk[2][r], sk[3][r]));
      mx = fmaxf(mx, __shfl_xor(mx, 1));
      mx = fmaxf(mx, __shfl_xor(mx, 2));
      mx = fmaxf(mx, __shfl_xor(mx, 4));
      mx = fmaxf(mx, __shfl_xor(mx, 8));
      mnew[r] = fmaxf(m_i[r], mx);
      alpha[r] = __expf(m_i[r] - mnew[r]);
      m_i[r] = mnew[r];
    }
    float rsum[4] = {0.f, 0.f, 0.f, 0.f};
#pragma unroll
    for (int kg = 0; kg < 4; ++kg)
#pragma unroll
      for (int r = 0; r < 4; ++r) {
        float p = __expf(sk[kg][r] - mnew[r]);
        sk[kg][r] = p;
        rsum[r] += p;
      }
#pragma unroll
    for (int r = 0; r < 4; ++r) {
      float t = rsum[r];
      t += __shfl_xor(t, 1); t += __shfl_xor(t, 2);
      t += __shfl_xor(t, 4); t += __shfl_xor(t, 8);
      l_i[r] = l_i[r] * alpha[r] + t;
    }
#pragma unroll
    for (int dg = 0; dg < 4; ++dg)
#pragma unroll
      for (int r = 0; r < 4; ++r) oacc[dg][r] *= alpha[r];
    // P -> LDS (bf16, swizzled), then re-read in A-layout
#pragma unroll
    for (int kg = 0; kg < 4; ++kg) {
      const int col = kg * 16 + l16;
      const int cc = col >> 3, w8 = col & 7;
#pragma unroll
      for (int r = 0; r < 4; ++r) {
        const int row = quad * 4 + r;
        Pw[row * 64 + ((cc ^ (row & 7)) << 3) + w8] = f2bf(sk[kg][r]);
      }
    }
    __syncthreads();
#pragma unroll
    for (int c = 0; c < 2; ++c) {
      const int swp = l16 & 7;
      bf16x8 af = *(const bf16x8*)(Pw + l16 * 64 + (((c * 4 + quad) ^ swp) << 3));
#pragma unroll
      for (int dg = 0; dg < 4; ++dg) {
        const int vrow = dg * 16 + l16;
        bf16x8 bv = *(const bf16x8*)(Vts + vrow * 64 + (((c * 4 + quad) ^ (vrow & 7)) << 3));
        oacc[dg] = __builtin_amdgcn_mfma_f32_16x16x32_bf16(af, bv, oacc[dg], 0, 0, 0);
      }
    }
  }
  // epilogue: O[q][dh] / l, write [B,T,D] bf16
#pragma unroll
  for (int dg = 0; dg < 4; ++dg)
#pragma unroll
    for (int r = 0; r < 4; ++r) {
      const int t = q0 + wave * 16 + quad * 4 + r;
      float o = oacc[dg][r] / l_i[r];
      Op[(size_t)t * KDM + dg * 16 + l16] = f2bf(o);
    }
}

// ================================================================ launcher
extern "C" void kernel_launch(void* const* d_in, const int* in_sizes, int n_in,
                              void* d_out, int out_size, void* d_ws, size_t ws_size,
                              hipStream_t stream) {
  const int*   idx  = (const int*)d_in[0];
  const float* img  = (const float*)d_in[1];
  const float* tok  = (const float*)d_in[2];
  const float* pos  = (const float*)d_in[3];
  const float* ln1w = (const float*)d_in[4];
  const float* ln1b = (const float*)d_in[5];
  const float* qkvw = (const float*)d_in[6];
  const float* outw = (const float*)d_in[7];
  const float* ln2w = (const float*)d_in[8];
  const float* ln2b = (const float*)d_in[9];
  const float* fc1w = (const float*)d_in[10];
  const float* fc1b = (const float*)d_in[11];
  const float* fc2w = (const float*)d_in[12];
  const float* fc2b = (const float*)d_in[13];
  const float* lnfw = (const float*)d_in[14];
  const float* lnfb = (const float*)d_in[15];
  const float* headw = (const float*)d_in[16];
  float* out = (float*)d_out;

  uint8_t* ws = (uint8_t*)d_ws;
  size_t off = 0;
  auto alloc = [&](size_t bytes) -> void* {
    void* p = ws + off;
    off += (bytes + 255) & ~(size_t)255;
    return p;
  };
  u16*  wqkv  = (u16*)alloc((size_t)3 * KDM * KDM * 2);
  u16*  wout  = (u16*)alloc((size_t)KDM * KDM * 2);
  u16*  wfc1  = (u16*)alloc((size_t)KDFF * KDM * 2);
  u16*  wfc2  = (u16*)alloc((size_t)KDM * KDFF * 2);
  u16*  whead = (u16*)alloc((size_t)KVOCAB * KDM * 2);
  float* x    = (float*)alloc((size_t)KBT * KDM * 4);
  u16*  hbuf  = (u16*)alloc((size_t)KBT * KDM * 2);     // ln out / attn O (reused)
  u16*  ffbuf = (u16*)alloc((size_t)KBT * KDFF * 2);
  u16*  Qb    = (u16*)alloc((size_t)KBATCH * KHEADS * KT * KDH * 2);
  u16*  Kb    = (u16*)alloc((size_t)KBATCH * KHEADS * KT * KDH * 2);
  u16*  Vtb   = (u16*)alloc((size_t)KBATCH * KHEADS * KDH * KT * 2);

  (void)in_sizes; (void)n_in; (void)out_size; (void)ws_size;

  // head weights -> bf16 (once)
  f32_to_bf16_k<<<KVOCAB * KDM / 4 / 256, 256, 0, stream>>>(headw, whead, KVOCAB * KDM / 4);
  // embeddings
  embed_k<<<KBT * KDM / 4 / 256, 256, 0, stream>>>(idx, img, tok, pos, x);

  for (int l = 0; l < KLAYERS; ++l) {
    f32_to_bf16_k<<<3 * KDM * KDM / 4 / 256, 256, 0, stream>>>(qkvw + (size_t)l * 3 * KDM * KDM, wqkv, 3 * KDM * KDM / 4);
    f32_to_bf16_k<<<KDM * KDM / 4 / 256, 256, 0, stream>>>(outw + (size_t)l * KDM * KDM, wout, KDM * KDM / 4);
    f32_to_bf16_k<<<KDFF * KDM / 4 / 256, 256, 0, stream>>>(fc1w + (size_t)l * KDFF * KDM, wfc1, KDFF * KDM / 4);
    f32_to_bf16_k<<<KDM * KDFF / 4 / 256, 256, 0, stream>>>(fc2w + (size_t)l * KDM * KDFF, wfc2, KDM * KDFF / 4);

    // ln1 -> QKV GEMM with fused repack (Q scaled, K, V^T) -> attention
    layernorm_k<<<KBT, 256, 0, stream>>>(x, ln1w + l * KDM, ln1b + l * KDM, hbuf, 0);
    gemm_nt<3><<<dim3(3 * KDM / 128, KBT / 128), 256, 0, stream>>>(
        hbuf, wqkv, 3 * KDM, KDM, nullptr, nullptr, nullptr, Qb, Kb, Vtb);
    attn_k<<<dim3(KT / 64, KBATCH * KHEADS), 256, 0, stream>>>(Qb, Kb, Vtb, hbuf);
    // out-proj GEMM with fused residual (x += O @ Wout^T)
    gemm_nt<2><<<dim3(KDM / 128, KBT / 128), 256, 0, stream>>>(
        hbuf, wout, KDM, KDM, x, nullptr, nullptr, nullptr, nullptr, nullptr);

    // ln2 -> FC1 GEMM with fused bias+relu -> bf16
    layernorm_k<<<KBT, 256, 0, stream>>>(x, ln2w + l * KDM, ln2b + l * KDM, hbuf, 0);
    gemm_nt<1><<<dim3(KDFF / 128, KBT / 128), 256, 0, stream>>>(
        hbuf, wfc1, KDFF, KDM, nullptr, fc1b + (size_t)l * KDFF, ffbuf, nullptr, nullptr, nullptr);
    // FC2 GEMM with fused residual + bias (x += FF @ Wfc2^T + b)
    gemm_nt<2><<<dim3(KDM / 128, KBT / 128), 256, 0, stream>>>(
        ffbuf, wfc2, KDM, KDFF, x, fc2b + (size_t)l * KDM, nullptr, nullptr, nullptr, nullptr);
  }

  layernorm_k<<<KMTXT, 256, 0, stream>>>(x, lnfw, lnfb, hbuf, 1);
  gemm_nt<0><<<dim3(KVOCAB / 128, KMTXT / 128), 256, 0, stream>>>(
      hbuf, whead, KVOCAB, KDM, out, nullptr, nullptr, nullptr, nullptr, nullptr);
}